// Round 3
// baseline (248.036 us; speedup 1.0000x reference)
//
#include <hip/hip_runtime.h>

// LengthRegulator: B=32, T=1024, D=384, T_OUT=4096
// out[b, p, :] = x[b, t(p), :] where t(p) = #{t : ends[t] <= p} (searchsorted
// right of inclusive-cumsum of max(dur,0)), valid for p < min(total, target).
//
// Two-kernel split:
//   lr_index  : per batch, shuffle-scan durations + searchsorted for all 4096
//               output rows -> int16 row table in d_ws (-1 == "write zeros").
//   lr_gather : pure gather/stream kernel.
//
// R3 single-variable change: NT stores -> PLAIN stores in lr_gather.
// Rationale: the harness's own fill kernel sustains 6.4 TB/s with plain
// stores through L2 write-combining at 9.7% occupancy / 8 VGPR; our NT
// stores (untested CUDA idiom inherited from the prior session) are the
// only unverified element left in a loop running at ~1.7 TB/s store-side.

#define BB 32
#define TT 1024
#define TOUT 4096
#define D4 96                // float4 per row (384/4)
#define N4 (TOUT * D4)       // 393216 float4 per batch
#define EPB 3072             // float4 per block = exactly 32 rows
#define ROWS_PB 32
#define KPT 12               // float4 per thread (EPB / 256)
#define IDX_GROUPS 4         // lr_index: blocks per batch (1024 rows each)

typedef float v4f __attribute__((ext_vector_type(4)));

// ---------------- kernel 1: duration scan + searchsorted -> int16 table ----
__global__ __launch_bounds__(256) void lr_index(
    const int4* __restrict__ dur4,      // [B, 256] durations as int4
    const int* __restrict__ target_len, // [B]
    short* __restrict__ t_idx)          // [B, TOUT]
{
    __shared__ int s_ends[TT];
    __shared__ int s_wsum[4];
    const int b = blockIdx.x;
    const int g = blockIdx.y;           // row-group: 1024 output rows
    const int tid = threadIdx.x;
    const int lane = tid & 63;
    const int wave = tid >> 6;
    const int tl = target_len[b];

    // in-block duration scan (4 durations/thread, shuffle-based)
    int4 d = dur4[b * 256 + tid];
    const int d0 = d.x > 0 ? d.x : 0;
    const int d1 = d.y > 0 ? d.y : 0;
    const int d2 = d.z > 0 ? d.z : 0;
    const int d3 = d.w > 0 ? d.w : 0;
    const int e0 = d0, e1 = e0 + d1, e2 = e1 + d2, e3 = e2 + d3;

    int v = e3;
    #pragma unroll
    for (int off = 1; off < 64; off <<= 1) {
        int u = __shfl_up(v, off, 64);
        if (lane >= off) v += u;
    }
    if (lane == 63) s_wsum[wave] = v;
    __syncthreads();

    int wbase = 0;
    #pragma unroll
    for (int w = 0; w < 3; ++w) wbase += (w < wave) ? s_wsum[w] : 0;
    const int total = s_wsum[0] + s_wsum[1] + s_wsum[2] + s_wsum[3];
    const int lim = total < tl ? total : tl;

    const int base = wbase + v - e3;  // exclusive prefix for this thread's 4
    ((int4*)s_ends)[tid] = make_int4(base + e0, base + e1, base + e2, base + e3);
    __syncthreads();

    // 4 binary searches per thread (independent -> LDS latency pipelines)
    short* __restrict__ trow_b = t_idx + b * TOUT;
    #pragma unroll
    for (int k = 0; k < 4; ++k) {
        const int p = g * 1024 + k * 256 + tid;
        int lo = 0;
        #pragma unroll
        for (int s = 512; s > 0; s >>= 1) {
            lo += (s_ends[lo + s - 1] <= p) ? s : 0;   // lo stays in [0,1023]
        }
        trow_b[p] = (p < lim) ? (short)lo : (short)-1;
    }
}

// ---------------- kernel 2: pure gather/stream --------------------------
__global__ __launch_bounds__(256) void lr_gather(
    const short* __restrict__ t_idx,    // [B, TOUT]
    const v4f* __restrict__ x,          // [B, T, D4]
    v4f* __restrict__ out)              // [B, TOUT, D4]
{
    __shared__ short s_trow[ROWS_PB];
    const int b = blockIdx.y;
    const int tid = threadIdx.x;
    const int base0 = blockIdx.x * EPB;
    const int p0 = blockIdx.x * ROWS_PB;

    if (tid < ROWS_PB) s_trow[tid] = t_idx[b * TOUT + p0 + tid];
    __syncthreads();

    const v4f* __restrict__ x_b = x + b * TT * D4;
    v4f* __restrict__ out_b = out + b * N4;

    int tt[KPT], cc[KPT];
    #pragma unroll
    for (int k = 0; k < KPT; ++k) {
        const int i = base0 + k * 256 + tid;
        const int p = i / D4;            // magic-mul division
        cc[k] = i - p * D4;
        tt[k] = s_trow[p - p0];          // LDS broadcast; sign-extends
    }

    v4f vv[KPT];
    #pragma unroll
    for (int k = 0; k < KPT; ++k) {
        v4f val = (v4f)(0.f);
        const int t = tt[k];
        if (t >= 0) val = x_b[t * D4 + cc[k]];  // wave-coherent branch
        vv[k] = val;
    }

    // R3: plain stores (L2 write-combining path), was __builtin_nontemporal_store
    #pragma unroll
    for (int k = 0; k < KPT; ++k) {
        out_b[base0 + k * 256 + tid] = vv[k];
    }
}

// ---------------- fallback: original fused kernel (dead when ws present) --
__global__ __launch_bounds__(256) void lr_fused(
    const int4* __restrict__ dur4,
    const int* __restrict__ target_len,
    const v4f* __restrict__ x,
    v4f* __restrict__ out)
{
    __shared__ int s_ends[TT];
    __shared__ int s_wsum[4];
    __shared__ int s_trow[ROWS_PB];
    const int b = blockIdx.y;
    const int tid = threadIdx.x;
    const int lane = tid & 63;
    const int wave = tid >> 6;
    const int base0 = blockIdx.x * EPB;
    const int p0 = blockIdx.x * ROWS_PB;

    const int tl = target_len[b];

    int4 d = dur4[b * 256 + tid];
    const int d0 = d.x > 0 ? d.x : 0;
    const int d1 = d.y > 0 ? d.y : 0;
    const int d2 = d.z > 0 ? d.z : 0;
    const int d3 = d.w > 0 ? d.w : 0;
    const int e0 = d0, e1 = e0 + d1, e2 = e1 + d2, e3 = e2 + d3;

    int v = e3;
    #pragma unroll
    for (int off = 1; off < 64; off <<= 1) {
        int u = __shfl_up(v, off, 64);
        if (lane >= off) v += u;
    }
    if (lane == 63) s_wsum[wave] = v;
    __syncthreads();

    int wbase = 0;
    #pragma unroll
    for (int w = 0; w < 3; ++w) wbase += (w < wave) ? s_wsum[w] : 0;
    const int total = s_wsum[0] + s_wsum[1] + s_wsum[2] + s_wsum[3];
    const int lim = total < tl ? total : tl;

    const int base = wbase + v - e3;
    ((int4*)s_ends)[tid] = make_int4(base + e0, base + e1, base + e2, base + e3);
    __syncthreads();

    if (tid < ROWS_PB) {
        const int p = p0 + tid;
        int lo = 0;
        #pragma unroll
        for (int s = 512; s > 0; s >>= 1) {
            lo += (s_ends[lo + s - 1] <= p) ? s : 0;
        }
        s_trow[tid] = lo;
    }
    __syncthreads();

    const v4f* __restrict__ x_b = x + b * TT * D4;
    v4f* __restrict__ out_b = out + b * N4;

    int pp[KPT], ccc[KPT], ttt[KPT];
    v4f vv[KPT];
    #pragma unroll
    for (int k = 0; k < KPT; ++k) {
        const int i = base0 + k * 256 + tid;
        const int p = i / D4;
        pp[k] = p;
        ccc[k] = i - p * D4;
        ttt[k] = s_trow[p - p0];
    }
    #pragma unroll
    for (int k = 0; k < KPT; ++k) {
        vv[k] = x_b[ttt[k] * D4 + ccc[k]];
    }
    #pragma unroll
    for (int k = 0; k < KPT; ++k) {
        if (pp[k] >= lim) vv[k] = (v4f)(0.f);
        out_b[base0 + k * 256 + tid] = vv[k];
    }
}

extern "C" void kernel_launch(void* const* d_in, const int* in_sizes, int n_in,
                              void* d_out, int out_size, void* d_ws, size_t ws_size,
                              hipStream_t stream) {
    const float* x        = (const float*)d_in[0];
    const int* durations  = (const int*)d_in[1];
    const int* target_len = (const int*)d_in[2];
    float* out            = (float*)d_out;

    const size_t need = (size_t)BB * TOUT * sizeof(short);  // 256 KB
    if (d_ws != nullptr && ws_size >= need) {
        short* t_idx = (short*)d_ws;
        lr_index<<<dim3(BB, IDX_GROUPS), 256, 0, stream>>>(
            (const int4*)durations, target_len, t_idx);
        lr_gather<<<dim3(N4 / EPB, BB), 256, 0, stream>>>(
            t_idx, (const v4f*)x, (v4f*)out);
    } else {
        lr_fused<<<dim3(N4 / EPB, BB), 256, 0, stream>>>(
            (const int4*)durations, target_len, (const v4f*)x, (v4f*)out);
    }
}

// Round 4
// 239.842 us; speedup vs baseline: 1.0342x; 1.0342x over previous
//
#include <hip/hip_runtime.h>

// LengthRegulator: B=32, T=1024, D=384, T_OUT=4096
// out[b, p, :] = x[b, t(p), :] where t(p) = #{t : ends[t] <= p} (searchsorted
// right of inclusive-cumsum of max(dur,0)), valid for p < min(total, target).
//
// R4: back to the measured-best single fused kernel (241.3 us) with NT
// stores, ONE launch, plus an XCD-aware block swizzle: 4096 blocks are
// remapped so each of the 8 XCDs owns 4 complete batches' contiguous
// output range. Consecutive chunks of one batch share x rows; clustering
// them on one XCD makes the x read stream L2-resident per XCD instead of
// 8-way replicated across non-coherent L2s (the 768 MiB per-iteration
// poison flushes L2+L3, so without this, x reads go cold every iteration).

#define BB 32
#define TT 1024
#define TOUT 4096
#define D4 96                // float4 per row (384/4)
#define N4 (TOUT * D4)       // 393216 float4 per batch
#define EPB 3072             // float4 per block = exactly 32 rows
#define ROWS_PB 32
#define KPT 12               // float4 per thread (EPB / 256)
#define NBLK (BB * (N4 / EPB))   // 4096 total blocks
#define NXCD 8
#define PER_XCD (NBLK / NXCD)    // 512

typedef float v4f __attribute__((ext_vector_type(4)));

__global__ __launch_bounds__(256) void lr_fused(
    const int4* __restrict__ dur4,      // [B, 256] (durations viewed as int4)
    const int* __restrict__ target_len, // [B]
    const v4f* __restrict__ x,          // [B, T, D4]
    v4f* __restrict__ out)              // [B, TOUT, D4]
{
    __shared__ int s_ends[TT];
    __shared__ int s_wsum[4];
    __shared__ int s_trow[ROWS_PB];

    // ---- XCD-aware swizzle: dispatch round-robins flat id across XCDs; ----
    // map so XCD k gets newid range [k*512, (k+1)*512) = batches 4k..4k+3.
    const int flat = blockIdx.x;
    const int newid = (flat & (NXCD - 1)) * PER_XCD + (flat >> 3);
    const int b = newid >> 7;           // /128 chunks per batch
    const int chunk = newid & 127;

    const int tid = threadIdx.x;
    const int lane = tid & 63;
    const int wave = tid >> 6;
    const int base0 = chunk * EPB;
    const int p0 = chunk * ROWS_PB;

    const int tl = target_len[b];               // hoisted, hides under scan

    // ---- in-block duration scan (4 durations/thread, shuffle-based) ----
    int4 d = dur4[b * 256 + tid];
    const int d0 = d.x > 0 ? d.x : 0;
    const int d1 = d.y > 0 ? d.y : 0;
    const int d2 = d.z > 0 ? d.z : 0;
    const int d3 = d.w > 0 ? d.w : 0;
    const int e0 = d0, e1 = e0 + d1, e2 = e1 + d2, e3 = e2 + d3;

    // 64-lane inclusive scan of per-thread sums (6 shuffle steps, no barrier)
    int v = e3;
    #pragma unroll
    for (int off = 1; off < 64; off <<= 1) {
        int u = __shfl_up(v, off, 64);
        if (lane >= off) v += u;
    }
    if (lane == 63) s_wsum[wave] = v;
    __syncthreads();

    int wbase = 0;
    #pragma unroll
    for (int w = 0; w < 3; ++w) wbase += (w < wave) ? s_wsum[w] : 0;
    const int total = s_wsum[0] + s_wsum[1] + s_wsum[2] + s_wsum[3];
    const int lim = total < tl ? total : tl;

    const int base = wbase + v - e3;  // exclusive prefix for this thread's 4
    ((int4*)s_ends)[tid] = make_int4(base + e0, base + e1, base + e2, base + e3);
    __syncthreads();

    // ---- one binary search per output row this block covers ----
    if (tid < ROWS_PB) {
        const int p = p0 + tid;
        int lo = 0;
        #pragma unroll
        for (int s = 512; s > 0; s >>= 1) {
            lo += (s_ends[lo + s - 1] <= p) ? s : 0;   // lo stays in [0,1023]
        }
        s_trow[tid] = lo;
    }
    __syncthreads();

    // ---- gather: 12 float4/thread strided by 256 (wave-contiguous 4 KB
    // stores -> full HBM lines; 12 independent loads in flight) ----
    const v4f* __restrict__ x_b = x + b * TT * D4;
    v4f* __restrict__ out_b = out + b * N4;

    int pp[KPT], cc[KPT], tt[KPT];
    v4f vv[KPT];
    #pragma unroll
    for (int k = 0; k < KPT; ++k) {
        const int i = base0 + k * 256 + tid;
        const int p = i / D4;            // magic-mul division
        pp[k] = p;
        cc[k] = i - p * D4;
        tt[k] = s_trow[p - p0];          // LDS broadcast
    }
    #pragma unroll
    for (int k = 0; k < KPT; ++k) {
        vv[k] = x_b[tt[k] * D4 + cc[k]];
    }
    #pragma unroll
    for (int k = 0; k < KPT; ++k) {
        if (pp[k] >= lim) vv[k] = (v4f)(0.f);
        __builtin_nontemporal_store(vv[k], out_b + base0 + k * 256 + tid);
    }
}

extern "C" void kernel_launch(void* const* d_in, const int* in_sizes, int n_in,
                              void* d_out, int out_size, void* d_ws, size_t ws_size,
                              hipStream_t stream) {
    const float* x        = (const float*)d_in[0];
    const int* durations  = (const int*)d_in[1];
    const int* target_len = (const int*)d_in[2];
    float* out            = (float*)d_out;

    lr_fused<<<dim3(NBLK), 256, 0, stream>>>((const int4*)durations, target_len,
                                             (const v4f*)x, (v4f*)out);
}

// Round 5
// 239.774 us; speedup vs baseline: 1.0345x; 1.0003x over previous
//
#include <hip/hip_runtime.h>

// LengthRegulator: B=32, T=1024, D=384, T_OUT=4096
// out[b, p, :] = x[b, t(p), :] where t(p) = #{t : ends[t] <= p} (searchsorted
// right of inclusive-cumsum of max(dur,0)), valid for p < min(total, target).
//
// R5: attack read-side memory-level parallelism. The per-iteration 805 MB
// poison flushes L2/L3, so x reads are cold (~900 cy). The old per-thread
// gather holds only ~3.8 KB/CU of reads in flight -> ~2.4 TB/s ceiling
// (Little's law), matching the observed kernel time. Fix: each block's 32
// output rows map to a CONTIGUOUS x-row range [t_lo, t_hi] (~9 rows avg);
// stage it into LDS with global_load_lds (fire-and-forget DMA, no VGPR
// round trip, deep queue -> streaming-read behavior like the fill), then
// gather from LDS and NT-store. Rare wide-range blocks (>30 rows, ~6-sigma)
// take the old global-gather fallback, block-uniformly.

#define BB 32
#define TT 1024
#define TOUT 4096
#define D4 96                // float4 per row (384/4)
#define N4 (TOUT * D4)       // 393216 float4 per batch
#define EPB 3072             // float4 per block = exactly 32 rows
#define ROWS_PB 32
#define KPT 12               // float4 per thread (EPB / 256)
#define NBLK 4096
#define NXCD 8
#define PER_XCD (NBLK / NXCD)    // 512
#define SROWS 30             // staged x rows (46 KB); P(range>30) ~ 1e-9
#define ROWB (D4 * 16)       // 1536 bytes per x row
#define SBYTES (SROWS * ROWB)

typedef float v4f __attribute__((ext_vector_type(4)));

__global__ __launch_bounds__(256) void lr_fused(
    const int4* __restrict__ dur4,      // [B, 256] (durations viewed as int4)
    const int* __restrict__ target_len, // [B]
    const v4f* __restrict__ x,          // [B, T, D4]
    v4f* __restrict__ out)              // [B, TOUT, D4]
{
    __shared__ int s_ends[TT];
    __shared__ int s_wsum[4];
    __shared__ int s_trow[ROWS_PB];
    __shared__ v4f s_x[(SBYTES + 1024) / 16];   // +1 KB slack for last chunk

    // ---- XCD-aware swizzle (neutral-to-positive, kept from R4) ----
    const int flat = blockIdx.x;
    const int newid = (flat & (NXCD - 1)) * PER_XCD + (flat >> 3);
    const int b = newid >> 7;           // 128 chunks per batch
    const int chunk = newid & 127;

    const int tid = threadIdx.x;
    const int lane = tid & 63;
    const int wave = tid >> 6;
    const int base0 = chunk * EPB;
    const int p0 = chunk * ROWS_PB;

    const int tl = target_len[b];               // hoisted, hides under scan

    // ---- in-block duration scan (4 durations/thread, shuffle-based) ----
    int4 d = dur4[b * 256 + tid];
    const int d0 = d.x > 0 ? d.x : 0;
    const int d1 = d.y > 0 ? d.y : 0;
    const int d2 = d.z > 0 ? d.z : 0;
    const int d3 = d.w > 0 ? d.w : 0;
    const int e0 = d0, e1 = e0 + d1, e2 = e1 + d2, e3 = e2 + d3;

    int v = e3;
    #pragma unroll
    for (int off = 1; off < 64; off <<= 1) {
        int u = __shfl_up(v, off, 64);
        if (lane >= off) v += u;
    }
    if (lane == 63) s_wsum[wave] = v;
    __syncthreads();

    int wbase = 0;
    #pragma unroll
    for (int w = 0; w < 3; ++w) wbase += (w < wave) ? s_wsum[w] : 0;
    const int total = s_wsum[0] + s_wsum[1] + s_wsum[2] + s_wsum[3];
    const int lim = total < tl ? total : tl;

    const int base = wbase + v - e3;  // exclusive prefix for this thread's 4
    ((int4*)s_ends)[tid] = make_int4(base + e0, base + e1, base + e2, base + e3);
    __syncthreads();

    // ---- one binary search per output row this block covers ----
    if (tid < ROWS_PB) {
        const int p = p0 + tid;
        int lo = 0;
        #pragma unroll
        for (int s = 512; s > 0; s >>= 1) {
            lo += (s_ends[lo + s - 1] <= p) ? s : 0;
        }
        s_trow[tid] = lo < (TT - 1) ? lo : (TT - 1);  // clamp like reference
    }
    __syncthreads();

    const v4f* __restrict__ x_b = x + b * TT * D4;
    v4f* __restrict__ out_b = out + b * N4;

    const int t_lo = s_trow[0];
    const int t_hi = s_trow[ROWS_PB - 1];       // monotone -> max
    const int nrows = t_hi - t_lo + 1;

    if (nrows <= SROWS) {
        // ---- stage [t_lo, t_hi] into LDS: streaming, fire-and-forget ----
        const int nbytes = nrows * ROWB;
        const char* gsrc = (const char*)(x_b + t_lo * D4);
        const char* gend = (const char*)(x_b + TT * D4) - 16;  // per-batch clamp
        for (int off = wave * 1024; off < nbytes; off += 4096) {
            const char* g = gsrc + off + (lane << 4);   // per-lane global src
            if (g > gend) g = gend;                     // tail clamp (unused slots)
            __builtin_amdgcn_global_load_lds(
                (const __attribute__((address_space(1))) void*)g,
                (__attribute__((address_space(3))) void*)((char*)s_x + off),
                16, 0, 0);                              // wave-uniform LDS base
        }
        __syncthreads();   // drains vmcnt(0) before LDS reads

        // ---- gather from LDS + NT store ----
        #pragma unroll
        for (int k = 0; k < KPT; ++k) {
            const int i = base0 + k * 256 + tid;
            const int p = i / D4;                // magic-mul division
            const int c = i - p * D4;
            const int t = s_trow[p - p0];
            v4f val = s_x[(t - t_lo) * D4 + c];
            if (p >= lim) val = (v4f)(0.f);
            __builtin_nontemporal_store(val, out_b + i);
        }
    } else {
        // ---- rare fallback: per-thread global gather (block-uniform) ----
        int pp[KPT], cc[KPT], tt[KPT];
        v4f vv[KPT];
        #pragma unroll
        for (int k = 0; k < KPT; ++k) {
            const int i = base0 + k * 256 + tid;
            const int p = i / D4;
            pp[k] = p;
            cc[k] = i - p * D4;
            tt[k] = s_trow[p - p0];
        }
        #pragma unroll
        for (int k = 0; k < KPT; ++k) {
            vv[k] = x_b[tt[k] * D4 + cc[k]];
        }
        #pragma unroll
        for (int k = 0; k < KPT; ++k) {
            if (pp[k] >= lim) vv[k] = (v4f)(0.f);
            __builtin_nontemporal_store(vv[k], out_b + base0 + k * 256 + tid);
        }
    }
}

extern "C" void kernel_launch(void* const* d_in, const int* in_sizes, int n_in,
                              void* d_out, int out_size, void* d_ws, size_t ws_size,
                              hipStream_t stream) {
    const float* x        = (const float*)d_in[0];
    const int* durations  = (const int*)d_in[1];
    const int* target_len = (const int*)d_in[2];
    float* out            = (float*)d_out;

    lr_fused<<<dim3(NBLK), 256, 0, stream>>>((const int4*)durations, target_len,
                                             (const v4f*)x, (v4f*)out);
}